// Round 1
// baseline (25414.487 us; speedup 1.0000x reference)
//
#include <hip/hip_runtime.h>

typedef __attribute__((ext_vector_type(8))) short s16x8;
typedef __attribute__((ext_vector_type(4))) float f32x4;

static __device__ __forceinline__ unsigned short f2bf(float f) {
    unsigned u = __float_as_uint(f);
    u = (u + 0x7fffu + ((u >> 16) & 1u)) >> 16;
    return (unsigned short)u;
}

__global__ void k_cast_bf16(const float* __restrict__ src,
                            unsigned short* __restrict__ dst, int n4) {
    int i = blockIdx.x * blockDim.x + threadIdx.x;
    int stride = gridDim.x * blockDim.x;
    for (; i < n4; i += stride) {
        float4 v = reinterpret_cast<const float4*>(src)[i];
        ushort4 o;
        o.x = f2bf(v.x); o.y = f2bf(v.y); o.z = f2bf(v.z); o.w = f2bf(v.w);
        reinterpret_cast<ushort4*>(dst)[i] = o;
    }
}

// Persistent GRU kernel: 256 blocks (one per CU), 256 threads (4 waves).
// Block (rb, jt): batch rows [rb*64, rb*64+64), hidden cols [jt*16, jt*16+16).
// Barrier groups = rb (batch-row blocks are independent).
__global__ __launch_bounds__(256, 1) void k_gru(
    const unsigned short* __restrict__ x16,    // [256][512][512]
    const unsigned short* __restrict__ wh,     // [3][1024][1024]  gates r,c,z
    const unsigned short* __restrict__ wx,     // [3][1024][512]
    const unsigned short* __restrict__ wo,     // [512][1024]
    const float* __restrict__ bxr_, const float* __restrict__ bhr_,
    const float* __restrict__ bxc_, const float* __restrict__ bhc_,
    const float* __restrict__ bxz_, const float* __restrict__ bhz_,
    const float* __restrict__ bo_,
    unsigned short* __restrict__ h16a,         // [256][1024] bf16, zeroed
    unsigned short* __restrict__ h16b,
    unsigned* __restrict__ cnt,                // 4 counters, 128B apart, zeroed
    float* __restrict__ out)                   // [256][512]
{
    extern __shared__ unsigned short lds[];    // 48 rows x 1536 bf16, swizzled

    const int tid = threadIdx.x;
    const int bid = blockIdx.x;
    const int xcd = bid & 7;
    const int rb  = xcd >> 1;                  // 0..3
    const int jt  = ((bid >> 3) << 1) | (xcd & 1); // 0..63
    const int b0  = rb * 64;
    const int j0  = jt * 16;

    // ---- stage weight tile into LDS once (rows: gate*16+jj, K=1536) ----
    // granule = 16B (8 bf16); 192 granules/row; 48*192 = 9216 granules.
    for (int i = 0; i < 36; ++i) {
        int gidx = i * 256 + tid;
        int rr = gidx / 192;
        int gc = gidx - rr * 192;
        int k  = gc << 3;
        int gate = rr >> 4;
        int j = j0 + (rr & 15);
        const unsigned short* src =
            (k < 1024) ? (wh + ((size_t)gate << 20) + ((size_t)j << 10) + k)
                       : (wx + (size_t)gate * 524288 + ((size_t)j << 9) + (k - 1024));
        s16x8 v = *reinterpret_cast<const s16x8*>(src);
        int boff = ((rr * 192 + gc) << 4) ^ ((rr & 7) << 4);
        *reinterpret_cast<s16x8*>(reinterpret_cast<char*>(lds) + boff) = v;
    }
    __syncthreads();

    const int lane = tid & 63;
    const int wv   = tid >> 6;
    const int l15  = lane & 15;
    const int lk   = lane >> 4;

    const int arow = b0 + wv * 16 + l15;       // A-fragment row (batch)
    const int swz  = (l15 & 7) << 4;
    const int rbase0 = (l15)      * 192 + lk;  // gate r LDS row base (granules)
    const int rbase1 = (16 + l15) * 192 + lk;  // gate c
    const int rbase2 = (32 + l15) * 192 + lk;  // gate z

    const int j = j0 + l15;                    // C-fragment col
    const float bR  = bxr_[j] + bhr_[j];
    const float bZ  = bxz_[j] + bhz_[j];
    const float bCh = bhc_[j];
    const float bCx = bxc_[j];

    float hreg[4] = {0.f, 0.f, 0.f, 0.f};      // h state, registers, fp32

    unsigned short* hc = h16a;
    unsigned short* hn = h16b;

    const unsigned short* xrowbase = x16 + (size_t)arow * 262144 + lk * 8;
    char* lb = reinterpret_cast<char*>(lds);

    for (int t = 0; t < 512; ++t) {
        f32x4 aR  = {0.f,0.f,0.f,0.f};
        f32x4 aZ  = {0.f,0.f,0.f,0.f};
        f32x4 aCh = {0.f,0.f,0.f,0.f};
        f32x4 aCx = {0.f,0.f,0.f,0.f};

        const unsigned short* ah = hc + ((size_t)arow << 10) + lk * 8;
#pragma unroll 4
        for (int kk = 0; kk < 32; ++kk) {
            s16x8 a  = *reinterpret_cast<const s16x8*>(ah + kk * 32);
            s16x8 b0f = *reinterpret_cast<const s16x8*>(lb + (((rbase0 + kk * 4) << 4) ^ swz));
            s16x8 b1f = *reinterpret_cast<const s16x8*>(lb + (((rbase1 + kk * 4) << 4) ^ swz));
            s16x8 b2f = *reinterpret_cast<const s16x8*>(lb + (((rbase2 + kk * 4) << 4) ^ swz));
            aR  = __builtin_amdgcn_mfma_f32_16x16x32_bf16(a, b0f, aR, 0, 0, 0);
            aCh = __builtin_amdgcn_mfma_f32_16x16x32_bf16(a, b1f, aCh, 0, 0, 0);
            aZ  = __builtin_amdgcn_mfma_f32_16x16x32_bf16(a, b2f, aZ, 0, 0, 0);
        }
        const unsigned short* ax = xrowbase + (size_t)t * 512;
#pragma unroll 4
        for (int kk = 32; kk < 48; ++kk) {
            s16x8 a  = *reinterpret_cast<const s16x8*>(ax + (kk - 32) * 32);
            s16x8 b0f = *reinterpret_cast<const s16x8*>(lb + (((rbase0 + kk * 4) << 4) ^ swz));
            s16x8 b1f = *reinterpret_cast<const s16x8*>(lb + (((rbase1 + kk * 4) << 4) ^ swz));
            s16x8 b2f = *reinterpret_cast<const s16x8*>(lb + (((rbase2 + kk * 4) << 4) ^ swz));
            aR  = __builtin_amdgcn_mfma_f32_16x16x32_bf16(a, b0f, aR, 0, 0, 0);
            aCx = __builtin_amdgcn_mfma_f32_16x16x32_bf16(a, b1f, aCx, 0, 0, 0);
            aZ  = __builtin_amdgcn_mfma_f32_16x16x32_bf16(a, b2f, aZ, 0, 0, 0);
        }

        // elementwise gate math, h in registers (rows = b0+wv*16+lk*4+e, col = j)
#pragma unroll
        for (int e = 0; e < 4; ++e) {
            float r   = 1.f / (1.f + __expf(-(aR[e] + bR)));
            float zg  = 1.f / (1.f + __expf(-(aZ[e] + bZ)));
            float cg  = tanhf(aCx[e] + bCx + r * (aCh[e] + bCh));
            float hnv = (1.f - zg) * hreg[e] + zg * cg;
            hreg[e] = hnv;
            hn[((size_t)(b0 + wv * 16 + lk * 4 + e) << 10) + j] = f2bf(hnv);
        }

        // ---- group barrier (64 WGs sharing this batch-row block) ----
        __threadfence();
        __syncthreads();
        if (tid == 0) {
            atomicAdd(&cnt[rb << 5], 1u);
            const unsigned tgt = (unsigned)(t + 1) * 64u;
            while (__hip_atomic_load(&cnt[rb << 5], __ATOMIC_RELAXED,
                                     __HIP_MEMORY_SCOPE_AGENT) < tgt)
                __builtin_amdgcn_s_sleep(4);
        }
        __syncthreads();
        __threadfence();

        unsigned short* tmp = hc; hc = hn; hn = tmp;
    }

    // ---- final projection: out = h_final @ Wo^T + bo  (hc == final h) ----
    const int ocol  = jt * 8 + l15;                      // valid when l15 < 8
    const int ocolc = (l15 < 8) ? ocol : (jt * 8 + 7);   // clamped for loads
    f32x4 aO = {0.f,0.f,0.f,0.f};
    const unsigned short* ah = hc + ((size_t)arow << 10) + lk * 8;
    const unsigned short* bw = wo + ((size_t)ocolc << 10) + lk * 8;
#pragma unroll 4
    for (int kk = 0; kk < 32; ++kk) {
        s16x8 a = *reinterpret_cast<const s16x8*>(ah + kk * 32);
        s16x8 b = *reinterpret_cast<const s16x8*>(bw + kk * 32);
        aO = __builtin_amdgcn_mfma_f32_16x16x32_bf16(a, b, aO, 0, 0, 0);
    }
    if (l15 < 8) {
        const float bov = bo_[ocol];
#pragma unroll
        for (int e = 0; e < 4; ++e) {
            out[((size_t)(b0 + wv * 16 + lk * 4 + e) << 9) + ocol] = aO[e] + bov;
        }
    }
}

extern "C" void kernel_launch(void* const* d_in, const int* in_sizes, int n_in,
                              void* d_out, int out_size, void* d_ws, size_t ws_size,
                              hipStream_t stream) {
    const float* x   = (const float*)d_in[0];
    const float* Wxr = (const float*)d_in[1];
    const float* bxr = (const float*)d_in[2];
    const float* Whr = (const float*)d_in[3];
    const float* bhr = (const float*)d_in[4];
    const float* Wxc = (const float*)d_in[5];
    const float* bxc = (const float*)d_in[6];
    const float* Whc = (const float*)d_in[7];
    const float* bhc = (const float*)d_in[8];
    const float* Wxz = (const float*)d_in[9];
    const float* bxz = (const float*)d_in[10];
    const float* Whz = (const float*)d_in[11];
    const float* bhz = (const float*)d_in[12];
    const float* Wo  = (const float*)d_in[13];
    const float* bo  = (const float*)d_in[14];

    char* ws = (char*)d_ws;
    unsigned short* x16  = (unsigned short*)(ws);                // 134217728 B
    unsigned short* wh   = (unsigned short*)(ws + 134217728);    //   6291456 B
    unsigned short* wx   = (unsigned short*)(ws + 140509184);    //   3145728 B
    unsigned short* wo16 = (unsigned short*)(ws + 143654912);    //   1048576 B
    unsigned short* h16a = (unsigned short*)(ws + 144703488);    //    524288 B
    unsigned short* h16b = (unsigned short*)(ws + 145227776);    //    524288 B
    unsigned*       cnt  = (unsigned*)(ws + 145752064);          //       512 B

    auto cast = [&](const float* s, unsigned short* d, int n) {
        int n4 = n >> 2;
        int blocks = (n4 + 255) / 256;
        if (blocks > 4096) blocks = 4096;
        k_cast_bf16<<<blocks, 256, 0, stream>>>(s, d, n4);
    };
    cast(x,   x16, 67108864);
    cast(Whr, wh,            1048576);
    cast(Whc, wh + 1048576,  1048576);
    cast(Whz, wh + 2097152,  1048576);
    cast(Wxr, wx,            524288);
    cast(Wxc, wx + 524288,   524288);
    cast(Wxz, wx + 1048576,  524288);
    cast(Wo,  wo16,          524288);

    hipMemsetAsync(h16a, 0, 524288, stream);
    hipMemsetAsync(cnt,  0, 512, stream);

    hipFuncSetAttribute(reinterpret_cast<const void*>(k_gru),
                        hipFuncAttributeMaxDynamicSharedMemorySize, 147456);
    k_gru<<<dim3(256), dim3(256), 147456, stream>>>(
        x16, wh, wx, wo16, bxr, bhr, bxc, bhc, bxz, bhz, bo,
        h16a, h16b, cnt, (float*)d_out);
}

// Round 2
// 7295.564 us; speedup vs baseline: 3.4836x; 3.4836x over previous
//
#include <hip/hip_runtime.h>

typedef __attribute__((ext_vector_type(8))) short s16x8;
typedef __attribute__((ext_vector_type(4))) float f32x4;

#define SCOPE_AGENT __HIP_MEMORY_SCOPE_AGENT

static __device__ __forceinline__ unsigned short f2bf(float f) {
    unsigned u = __float_as_uint(f);
    u = (u + 0x7fffu + ((u >> 16) & 1u)) >> 16;
    return (unsigned short)u;
}

__global__ void k_cast_bf16(const float* __restrict__ src,
                            unsigned short* __restrict__ dst, int n4) {
    int i = blockIdx.x * blockDim.x + threadIdx.x;
    int stride = gridDim.x * blockDim.x;
    for (; i < n4; i += stride) {
        float4 v = reinterpret_cast<const float4*>(src)[i];
        ushort4 o;
        o.x = f2bf(v.x); o.y = f2bf(v.y); o.z = f2bf(v.z); o.w = f2bf(v.w);
        reinterpret_cast<ushort4*>(dst)[i] = o;
    }
}

// Persistent GRU kernel: 256 blocks (one per CU), 256 threads (4 waves).
// Block (rb, jt): batch rows [rb*64, rb*64+64), hidden cols [jt*16, jt*16+16).
// h exchange: sc1 (agent-scope relaxed atomic) stores/loads through MALL —
// no dirty L2 → no threadfence/wbl2 needed. Barrier: per-WG monotone flag
// (slot[wg] = t+1) + wave-wide 64-slot poll with __all. __syncthreads()
// drains vmcnt(0) per wave = the release fence before the flag store.
__global__ __launch_bounds__(256, 1) void k_gru(
    const unsigned short* __restrict__ x16,    // [256][512][512] bf16
    const unsigned short* __restrict__ wh,     // [3][1024][1024]  gates r,c,z
    const unsigned short* __restrict__ wx,     // [3][1024][512]
    const unsigned short* __restrict__ wo,     // [512][1024]
    const float* __restrict__ bxr_, const float* __restrict__ bhr_,
    const float* __restrict__ bxc_, const float* __restrict__ bhc_,
    const float* __restrict__ bxz_, const float* __restrict__ bhz_,
    const float* __restrict__ bo_,
    unsigned short* __restrict__ h16a,         // [256][1024] bf16, zeroed
    unsigned short* __restrict__ h16b,
    unsigned* __restrict__ slots,              // [4][64] monotone step flags, zeroed
    float* __restrict__ out)                   // [256][512]
{
    extern __shared__ unsigned short lds[];    // 48 rows x 1536 bf16, swizzled

    const int tid = threadIdx.x;
    const int bid = blockIdx.x;
    const int xcd = bid & 7;
    const int rb  = xcd >> 1;                  // 0..3 batch-row group
    const int jt  = ((bid >> 3) << 1) | (xcd & 1); // 0..63 j-tile
    const int b0  = rb * 64;
    const int j0  = jt * 16;

    // ---- stage weight tile into LDS once (rows: gate*16+jj, K=1536) ----
    for (int i = 0; i < 36; ++i) {
        int gidx = i * 256 + tid;
        int rr = gidx / 192;
        int gc = gidx - rr * 192;
        int k  = gc << 3;
        int gate = rr >> 4;
        int j = j0 + (rr & 15);
        const unsigned short* src =
            (k < 1024) ? (wh + ((size_t)gate << 20) + ((size_t)j << 10) + k)
                       : (wx + (size_t)gate * 524288 + ((size_t)j << 9) + (k - 1024));
        s16x8 v = *reinterpret_cast<const s16x8*>(src);
        int boff = ((rr * 192 + gc) << 4) ^ ((rr & 7) << 4);
        *reinterpret_cast<s16x8*>(reinterpret_cast<char*>(lds) + boff) = v;
    }
    __syncthreads();

    const int lane = tid & 63;
    const int wv   = tid >> 6;
    const int l15  = lane & 15;
    const int lk   = lane >> 4;

    const int b   = b0 + wv * 16 + l15;        // batch row (B-operand outer idx)
    const int jq  = j0 + lk * 4;               // first of this thread's 4 j cols
    const int swz = (l15 & 7) << 4;
    const int rbase0 = (l15)      * 192 + lk;  // gate r LDS row base (granules)
    const int rbase1 = (16 + l15) * 192 + lk;  // gate c
    const int rbase2 = (32 + l15) * 192 + lk;  // gate z

    float bR[4], bZ[4], bCh[4], bCx[4];
#pragma unroll
    for (int e = 0; e < 4; ++e) {
        int j = jq + e;
        bR[e]  = bxr_[j] + bhr_[j];
        bZ[e]  = bxz_[j] + bhz_[j];
        bCh[e] = bhc_[j];
        bCx[e] = bxc_[j];
    }

    float hreg[4] = {0.f, 0.f, 0.f, 0.f};      // h[b][jq+e], fp32, in regs

    unsigned short* hc = h16a;
    unsigned short* hn = h16b;
    char* lb = reinterpret_cast<char*>(lds);
    const unsigned short* xrowbase = x16 + (size_t)b * 262144 + lk * 8;

    for (int t = 0; t < 512; ++t) {
        // ---- prefetch h fragments (coherent, from MALL) + x fragments ----
        s16x8 hf[32];
        const unsigned long long* hq =
            reinterpret_cast<const unsigned long long*>(hc + ((size_t)b << 10));
#pragma unroll
        for (int kk = 0; kk < 32; ++kk) {
            union { s16x8 v; unsigned long long q[2]; } u;
            u.q[0] = __hip_atomic_load(hq + lk * 2 + kk * 8,
                                       __ATOMIC_RELAXED, SCOPE_AGENT);
            u.q[1] = __hip_atomic_load(hq + lk * 2 + kk * 8 + 1,
                                       __ATOMIC_RELAXED, SCOPE_AGENT);
            hf[kk] = u.v;
        }
        s16x8 xf[16];
        const unsigned short* ax = xrowbase + (size_t)t * 512;
#pragma unroll
        for (int kk = 0; kk < 16; ++kk)
            xf[kk] = *reinterpret_cast<const s16x8*>(ax + kk * 32);

        f32x4 aR  = {0.f,0.f,0.f,0.f};
        f32x4 aZ  = {0.f,0.f,0.f,0.f};
        f32x4 aCh = {0.f,0.f,0.f,0.f};
        f32x4 aCx = {0.f,0.f,0.f,0.f};

        // ---- MFMA loop: A = weights (LDS), B = h/x (regs) ----
#pragma unroll
        for (int kk = 0; kk < 32; ++kk) {
            s16x8 w0 = *reinterpret_cast<s16x8*>(lb + (((rbase0 + kk * 4) << 4) ^ swz));
            s16x8 w1 = *reinterpret_cast<s16x8*>(lb + (((rbase1 + kk * 4) << 4) ^ swz));
            s16x8 w2 = *reinterpret_cast<s16x8*>(lb + (((rbase2 + kk * 4) << 4) ^ swz));
            aR  = __builtin_amdgcn_mfma_f32_16x16x32_bf16(w0, hf[kk], aR, 0, 0, 0);
            aCh = __builtin_amdgcn_mfma_f32_16x16x32_bf16(w1, hf[kk], aCh, 0, 0, 0);
            aZ  = __builtin_amdgcn_mfma_f32_16x16x32_bf16(w2, hf[kk], aZ, 0, 0, 0);
        }
#pragma unroll
        for (int kk = 32; kk < 48; ++kk) {
            s16x8 w0 = *reinterpret_cast<s16x8*>(lb + (((rbase0 + kk * 4) << 4) ^ swz));
            s16x8 w1 = *reinterpret_cast<s16x8*>(lb + (((rbase1 + kk * 4) << 4) ^ swz));
            s16x8 w2 = *reinterpret_cast<s16x8*>(lb + (((rbase2 + kk * 4) << 4) ^ swz));
            aR  = __builtin_amdgcn_mfma_f32_16x16x32_bf16(w0, xf[kk - 32], aR, 0, 0, 0);
            aCx = __builtin_amdgcn_mfma_f32_16x16x32_bf16(w1, xf[kk - 32], aCx, 0, 0, 0);
            aZ  = __builtin_amdgcn_mfma_f32_16x16x32_bf16(w2, xf[kk - 32], aZ, 0, 0, 0);
        }

        // ---- gate math; thread owns h[b][jq..jq+3] ----
        unsigned long long pack = 0ull;
#pragma unroll
        for (int e = 0; e < 4; ++e) {
            float r   = __builtin_amdgcn_rcpf(1.f + __expf(-(aR[e] + bR[e])));
            float zg  = __builtin_amdgcn_rcpf(1.f + __expf(-(aZ[e] + bZ[e])));
            float u2  = aCx[e] + bCx[e] + r * (aCh[e] + bCh[e]);
            float cg  = 1.f - 2.f * __builtin_amdgcn_rcpf(__expf(2.f * u2) + 1.f);
            float hnv = (1.f - zg) * hreg[e] + zg * cg;
            hreg[e] = hnv;
            pack |= (unsigned long long)f2bf(hnv) << (16 * e);
        }
        __hip_atomic_store(
            reinterpret_cast<unsigned long long*>(hn + ((size_t)b << 10) + jq),
            pack, __ATOMIC_RELAXED, SCOPE_AGENT);

        // ---- group barrier: flag + poll (no atomics RMW, no threadfence) ----
        __syncthreads();   // drains vmcnt(0) per wave => release for sc1 stores
        if (tid == 0)
            __hip_atomic_store(&slots[(rb << 6) + jt], (unsigned)(t + 1),
                               __ATOMIC_RELAXED, SCOPE_AGENT);
        {
            const unsigned tgt = (unsigned)(t + 1);
            for (;;) {
                unsigned v = __hip_atomic_load(&slots[(rb << 6) + lane],
                                               __ATOMIC_RELAXED, SCOPE_AGENT);
                if (__all((int)(v >= tgt))) break;
                __builtin_amdgcn_s_sleep(1);
            }
        }
        asm volatile("" ::: "memory");

        unsigned short* tmp = hc; hc = hn; hn = tmp;
    }

    // ---- final projection: out = h_final @ Wo^T + bo  (hc == final h) ----
    const int arow  = b;                                  // batch row
    const int ocol  = jt * 8 + l15;                       // valid when l15 < 8
    const int ocolc = (l15 < 8) ? ocol : (jt * 8 + 7);    // clamped for loads
    f32x4 aO = {0.f,0.f,0.f,0.f};
    const unsigned long long* hq =
        reinterpret_cast<const unsigned long long*>(hc + ((size_t)arow << 10));
    const unsigned short* bw = wo + ((size_t)ocolc << 10) + lk * 8;
#pragma unroll
    for (int kk = 0; kk < 32; ++kk) {
        union { s16x8 v; unsigned long long q[2]; } u;
        u.q[0] = __hip_atomic_load(hq + lk * 2 + kk * 8,
                                   __ATOMIC_RELAXED, SCOPE_AGENT);
        u.q[1] = __hip_atomic_load(hq + lk * 2 + kk * 8 + 1,
                                   __ATOMIC_RELAXED, SCOPE_AGENT);
        s16x8 wb = *reinterpret_cast<const s16x8*>(bw + kk * 32);
        aO = __builtin_amdgcn_mfma_f32_16x16x32_bf16(u.v, wb, aO, 0, 0, 0);
    }
    if (l15 < 8) {
        const float bov = bo_[ocol];
#pragma unroll
        for (int e = 0; e < 4; ++e) {
            out[((size_t)(b0 + wv * 16 + lk * 4 + e) << 9) + ocol] = aO[e] + bov;
        }
    }
}

extern "C" void kernel_launch(void* const* d_in, const int* in_sizes, int n_in,
                              void* d_out, int out_size, void* d_ws, size_t ws_size,
                              hipStream_t stream) {
    const float* x   = (const float*)d_in[0];
    const float* Wxr = (const float*)d_in[1];
    const float* bxr = (const float*)d_in[2];
    const float* Whr = (const float*)d_in[3];
    const float* bhr = (const float*)d_in[4];
    const float* Wxc = (const float*)d_in[5];
    const float* bxc = (const float*)d_in[6];
    const float* Whc = (const float*)d_in[7];
    const float* bhc = (const float*)d_in[8];
    const float* Wxz = (const float*)d_in[9];
    const float* bxz = (const float*)d_in[10];
    const float* Whz = (const float*)d_in[11];
    const float* bhz = (const float*)d_in[12];
    const float* Wo  = (const float*)d_in[13];
    const float* bo  = (const float*)d_in[14];

    char* ws = (char*)d_ws;
    unsigned short* x16  = (unsigned short*)(ws);                // 134217728 B
    unsigned short* wh   = (unsigned short*)(ws + 134217728);    //   6291456 B
    unsigned short* wx   = (unsigned short*)(ws + 140509184);    //   3145728 B
    unsigned short* wo16 = (unsigned short*)(ws + 143654912);    //   1048576 B
    unsigned short* h16a = (unsigned short*)(ws + 144703488);    //    524288 B
    unsigned short* h16b = (unsigned short*)(ws + 145227776);    //    524288 B
    unsigned*       slots= (unsigned*)(ws + 145752064);          //      1024 B

    auto cast = [&](const float* s, unsigned short* d, int n) {
        int n4 = n >> 2;
        int blocks = (n4 + 255) / 256;
        if (blocks > 4096) blocks = 4096;
        k_cast_bf16<<<blocks, 256, 0, stream>>>(s, d, n4);
    };
    cast(x,   x16, 67108864);
    cast(Whr, wh,            1048576);
    cast(Whc, wh + 1048576,  1048576);
    cast(Whz, wh + 2097152,  1048576);
    cast(Wxr, wx,            524288);
    cast(Wxc, wx + 524288,   524288);
    cast(Wxz, wx + 1048576,  524288);
    cast(Wo,  wo16,          524288);

    hipMemsetAsync(h16a, 0, 524288, stream);
    hipMemsetAsync(slots, 0, 1024, stream);

    hipFuncSetAttribute(reinterpret_cast<const void*>(k_gru),
                        hipFuncAttributeMaxDynamicSharedMemorySize, 147456);
    k_gru<<<dim3(256), dim3(256), 147456, stream>>>(
        x16, wh, wx, wo16, bxr, bhr, bxc, bhc, bxz, bhz, bo,
        h16a, h16b, slots, (float*)d_out);
}

// Round 3
// 5939.239 us; speedup vs baseline: 4.2791x; 1.2284x over previous
//
#include <hip/hip_runtime.h>

typedef __attribute__((ext_vector_type(8))) short s16x8;
typedef __attribute__((ext_vector_type(4))) float f32x4;

#define SCOPE_AGENT __HIP_MEMORY_SCOPE_AGENT

static __device__ __forceinline__ unsigned short f2bf(float f) {
    unsigned u = __float_as_uint(f);
    u = (u + 0x7fffu + ((u >> 16) & 1u)) >> 16;
    return (unsigned short)u;
}

static __device__ __forceinline__ unsigned ld_sc1(const unsigned* p) {
    return __hip_atomic_load(p, __ATOMIC_RELAXED, SCOPE_AGENT);
}
static __device__ __forceinline__ void st_sc1(unsigned* p, unsigned v) {
    __hip_atomic_store(p, v, __ATOMIC_RELAXED, SCOPE_AGENT);
}

__global__ void k_cast_bf16(const float* __restrict__ src,
                            unsigned short* __restrict__ dst, int n4) {
    int i = blockIdx.x * blockDim.x + threadIdx.x;
    int stride = gridDim.x * blockDim.x;
    for (; i < n4; i += stride) {
        float4 v = reinterpret_cast<const float4*>(src)[i];
        ushort4 o;
        o.x = f2bf(v.x); o.y = f2bf(v.y); o.z = f2bf(v.z); o.w = f2bf(v.w);
        reinterpret_cast<ushort4*>(dst)[i] = o;
    }
}

// Persistent GRU: 256 blocks x 256 threads. Block (rb, jt): batch rows
// [rb*64,+64), hidden cols [jt*16,+16). Weights in LDS (147KB, swizzled).
// Barrier: per-WG monotone flag -> master WG (jt==0) aggregates -> single
// release word per group. x-part MFMAs for t+1 overlap the barrier wait.
__global__ __launch_bounds__(256, 1) void k_gru(
    const unsigned short* __restrict__ x16,    // [256][512][512] bf16
    const unsigned short* __restrict__ wh,     // [3][1024][1024]
    const unsigned short* __restrict__ wx,     // [3][1024][512]
    const unsigned short* __restrict__ wo,     // [512][1024]
    const float* __restrict__ bxr_, const float* __restrict__ bhr_,
    const float* __restrict__ bxc_, const float* __restrict__ bhc_,
    const float* __restrict__ bxz_, const float* __restrict__ bhz_,
    const float* __restrict__ bo_,
    unsigned short* __restrict__ h16a,         // [256][1024] bf16, zeroed
    unsigned short* __restrict__ h16b,
    unsigned* __restrict__ slots,              // [4][64] monotone flags, zeroed
    unsigned* __restrict__ rel,                // [4] release words (256B apart)
    float* __restrict__ out)                   // [256][512]
{
    extern __shared__ unsigned short lds[];

    const int tid = threadIdx.x;
    const int bid = blockIdx.x;
    const int xcd = bid & 7;
    const int rb  = xcd >> 1;
    const int jt  = ((bid >> 3) << 1) | (xcd & 1);
    const int b0  = rb * 64;
    const int j0  = jt * 16;

    // ---- stage weight tile into LDS once ----
    for (int i = 0; i < 36; ++i) {
        int gidx = i * 256 + tid;
        int rr = gidx / 192;
        int gc = gidx - rr * 192;
        int k  = gc << 3;
        int gate = rr >> 4;
        int j = j0 + (rr & 15);
        const unsigned short* src =
            (k < 1024) ? (wh + ((size_t)gate << 20) + ((size_t)j << 10) + k)
                       : (wx + (size_t)gate * 524288 + ((size_t)j << 9) + (k - 1024));
        s16x8 v = *reinterpret_cast<const s16x8*>(src);
        int boff = ((rr * 192 + gc) << 4) ^ ((rr & 7) << 4);
        *reinterpret_cast<s16x8*>(reinterpret_cast<char*>(lds) + boff) = v;
    }
    __syncthreads();

    const int lane = tid & 63;
    const int wv   = tid >> 6;
    const int l15  = lane & 15;
    const int lk   = lane >> 4;

    const int b   = b0 + wv * 16 + l15;
    const int jq  = j0 + lk * 4;
    const int swz = (l15 & 7) << 4;
    const int rbase0 = (l15)      * 192 + lk;
    const int rbase1 = (16 + l15) * 192 + lk;
    const int rbase2 = (32 + l15) * 192 + lk;

    float bR[4], bZ[4], bCh[4], bCx[4];
#pragma unroll
    for (int e = 0; e < 4; ++e) {
        int j = jq + e;
        bR[e]  = bxr_[j] + bhr_[j];
        bZ[e]  = bxz_[j] + bhz_[j];
        bCh[e] = bhc_[j];
        bCx[e] = bxc_[j];
    }

    float hreg[4] = {0.f, 0.f, 0.f, 0.f};
    char* lb = reinterpret_cast<char*>(lds);
    const unsigned short* xrowbase = x16 + (size_t)b * 262144 + lk * 8;
    unsigned* myflag  = &slots[(rb << 6) + jt];
    unsigned* grel    = &rel[rb << 6];

    // ---- prologue: x-part accumulators for t=0 ----
    f32x4 xR = {0.f,0.f,0.f,0.f}, xZ = {0.f,0.f,0.f,0.f}, xC = {0.f,0.f,0.f,0.f};
    {
        s16x8 xf[16];
#pragma unroll
        for (int kk = 0; kk < 16; ++kk)
            xf[kk] = *reinterpret_cast<const s16x8*>(xrowbase + kk * 32);
#pragma unroll
        for (int kk = 0; kk < 16; ++kk) {
            s16x8 w0 = *reinterpret_cast<s16x8*>(lb + (((rbase0 + (kk + 32) * 4) << 4) ^ swz));
            s16x8 w1 = *reinterpret_cast<s16x8*>(lb + (((rbase1 + (kk + 32) * 4) << 4) ^ swz));
            s16x8 w2 = *reinterpret_cast<s16x8*>(lb + (((rbase2 + (kk + 32) * 4) << 4) ^ swz));
            xR = __builtin_amdgcn_mfma_f32_16x16x32_bf16(w0, xf[kk], xR, 0, 0, 0);
            xC = __builtin_amdgcn_mfma_f32_16x16x32_bf16(w1, xf[kk], xC, 0, 0, 0);
            xZ = __builtin_amdgcn_mfma_f32_16x16x32_bf16(w2, xf[kk], xZ, 0, 0, 0);
        }
    }

    unsigned short* hc = h16a;                 // holds h_t (h_0 zeroed)
    unsigned short* hn = h16b;

    for (int t = 0; t < 512; ++t) {
        // ---- wait for h_t (t=0 passes: rel starts at 0) ----
        if (wv == 0) {
            while (ld_sc1(grel) < (unsigned)t) __builtin_amdgcn_s_sleep(1);
        }
        __syncthreads();
        asm volatile("" ::: "memory");

        // ---- load h_t fragments (coherent via MALL) ----
        s16x8 hf[32];
        const unsigned long long* hq =
            reinterpret_cast<const unsigned long long*>(hc + ((size_t)b << 10));
#pragma unroll
        for (int kk = 0; kk < 32; ++kk) {
            union { s16x8 v; unsigned long long q[2]; } u;
            u.q[0] = __hip_atomic_load(hq + lk * 2 + kk * 8,
                                       __ATOMIC_RELAXED, SCOPE_AGENT);
            u.q[1] = __hip_atomic_load(hq + lk * 2 + kk * 8 + 1,
                                       __ATOMIC_RELAXED, SCOPE_AGENT);
            hf[kk] = u.v;
        }
        // ---- prefetch x fragments for t+1 (consumed post-barrier) ----
        s16x8 xfn[16];
        if (t < 511) {
            const unsigned short* axn = xrowbase + (size_t)(t + 1) * 512;
#pragma unroll
            for (int kk = 0; kk < 16; ++kk)
                xfn[kk] = *reinterpret_cast<const s16x8*>(axn + kk * 32);
        }

        // ---- h-part MFMAs, accs seeded from x-part ----
        f32x4 aR = xR, aZ = xZ, aCx = xC;
        f32x4 aCh = {0.f,0.f,0.f,0.f};
#pragma unroll
        for (int kk = 0; kk < 32; ++kk) {
            s16x8 w0 = *reinterpret_cast<s16x8*>(lb + (((rbase0 + kk * 4) << 4) ^ swz));
            s16x8 w1 = *reinterpret_cast<s16x8*>(lb + (((rbase1 + kk * 4) << 4) ^ swz));
            s16x8 w2 = *reinterpret_cast<s16x8*>(lb + (((rbase2 + kk * 4) << 4) ^ swz));
            aR  = __builtin_amdgcn_mfma_f32_16x16x32_bf16(w0, hf[kk], aR, 0, 0, 0);
            aCh = __builtin_amdgcn_mfma_f32_16x16x32_bf16(w1, hf[kk], aCh, 0, 0, 0);
            aZ  = __builtin_amdgcn_mfma_f32_16x16x32_bf16(w2, hf[kk], aZ, 0, 0, 0);
        }

        // ---- gate math; store own h_{t+1} ----
        unsigned long long pack = 0ull;
#pragma unroll
        for (int e = 0; e < 4; ++e) {
            float r   = __builtin_amdgcn_rcpf(1.f + __expf(-(aR[e] + bR[e])));
            float zg  = __builtin_amdgcn_rcpf(1.f + __expf(-(aZ[e] + bZ[e])));
            float u2  = aCx[e] + bCx[e] + r * (aCh[e] + bCh[e]);
            float cg  = 1.f - 2.f * __builtin_amdgcn_rcpf(__expf(2.f * u2) + 1.f);
            float hnv = (1.f - zg) * hreg[e] + zg * cg;
            hreg[e] = hnv;
            pack |= (unsigned long long)f2bf(hnv) << (16 * e);
        }
        __hip_atomic_store(
            reinterpret_cast<unsigned long long*>(hn + ((size_t)b << 10) + jq),
            pack, __ATOMIC_RELAXED, SCOPE_AGENT);

        __syncthreads();   // drains vmcnt(0): h store + xfn loads complete
        if (tid == 0) st_sc1(myflag, (unsigned)(t + 1));

        // ---- master aggregates flags -> release ----
        if (jt == 0 && wv == 0) {
            const unsigned tgt = (unsigned)(t + 1);
            for (;;) {
                unsigned v = ld_sc1(&slots[(rb << 6) + lane]);
                if (__all((int)(v >= tgt))) break;
                __builtin_amdgcn_s_sleep(1);
            }
            if (tid == 0) st_sc1(grel, tgt);
        }

        // ---- x-part MFMAs for t+1 (overlaps barrier wait of others) ----
        if (t < 511) {
            xR = {0.f,0.f,0.f,0.f}; xZ = {0.f,0.f,0.f,0.f}; xC = {0.f,0.f,0.f,0.f};
#pragma unroll
            for (int kk = 0; kk < 16; ++kk) {
                s16x8 w0 = *reinterpret_cast<s16x8*>(lb + (((rbase0 + (kk + 32) * 4) << 4) ^ swz));
                s16x8 w1 = *reinterpret_cast<s16x8*>(lb + (((rbase1 + (kk + 32) * 4) << 4) ^ swz));
                s16x8 w2 = *reinterpret_cast<s16x8*>(lb + (((rbase2 + (kk + 32) * 4) << 4) ^ swz));
                xR = __builtin_amdgcn_mfma_f32_16x16x32_bf16(w0, xfn[kk], xR, 0, 0, 0);
                xC = __builtin_amdgcn_mfma_f32_16x16x32_bf16(w1, xfn[kk], xC, 0, 0, 0);
                xZ = __builtin_amdgcn_mfma_f32_16x16x32_bf16(w2, xfn[kk], xZ, 0, 0, 0);
            }
        }

        unsigned short* tmp = hc; hc = hn; hn = tmp;
    }

    // ---- wait for full h_512, then output projection ----
    if (wv == 0) {
        while (ld_sc1(grel) < 512u) __builtin_amdgcn_s_sleep(1);
    }
    __syncthreads();
    asm volatile("" ::: "memory");

    const int ocol  = jt * 8 + l15;
    const int ocolc = (l15 < 8) ? ocol : (jt * 8 + 7);
    f32x4 aO = {0.f,0.f,0.f,0.f};
    const unsigned long long* hq =
        reinterpret_cast<const unsigned long long*>(hc + ((size_t)b << 10));
    const unsigned short* bw = wo + ((size_t)ocolc << 10) + lk * 8;
#pragma unroll
    for (int kk = 0; kk < 32; ++kk) {
        union { s16x8 v; unsigned long long q[2]; } u;
        u.q[0] = __hip_atomic_load(hq + lk * 2 + kk * 8,
                                   __ATOMIC_RELAXED, SCOPE_AGENT);
        u.q[1] = __hip_atomic_load(hq + lk * 2 + kk * 8 + 1,
                                   __ATOMIC_RELAXED, SCOPE_AGENT);
        s16x8 wb = *reinterpret_cast<const s16x8*>(bw + kk * 32);
        aO = __builtin_amdgcn_mfma_f32_16x16x32_bf16(u.v, wb, aO, 0, 0, 0);
    }
    if (l15 < 8) {
        const float bov = bo_[ocol];
#pragma unroll
        for (int e = 0; e < 4; ++e) {
            out[((size_t)(b0 + wv * 16 + lk * 4 + e) << 9) + ocol] = aO[e] + bov;
        }
    }
}

extern "C" void kernel_launch(void* const* d_in, const int* in_sizes, int n_in,
                              void* d_out, int out_size, void* d_ws, size_t ws_size,
                              hipStream_t stream) {
    const float* x   = (const float*)d_in[0];
    const float* Wxr = (const float*)d_in[1];
    const float* bxr = (const float*)d_in[2];
    const float* Whr = (const float*)d_in[3];
    const float* bhr = (const float*)d_in[4];
    const float* Wxc = (const float*)d_in[5];
    const float* bxc = (const float*)d_in[6];
    const float* Whc = (const float*)d_in[7];
    const float* bhc = (const float*)d_in[8];
    const float* Wxz = (const float*)d_in[9];
    const float* bxz = (const float*)d_in[10];
    const float* Whz = (const float*)d_in[11];
    const float* bhz = (const float*)d_in[12];
    const float* Wo  = (const float*)d_in[13];
    const float* bo  = (const float*)d_in[14];

    char* ws = (char*)d_ws;
    unsigned short* x16  = (unsigned short*)(ws);                // 134217728 B
    unsigned short* wh   = (unsigned short*)(ws + 134217728);    //   6291456 B
    unsigned short* wx   = (unsigned short*)(ws + 140509184);    //   3145728 B
    unsigned short* wo16 = (unsigned short*)(ws + 143654912);    //   1048576 B
    unsigned short* h16a = (unsigned short*)(ws + 144703488);    //    524288 B
    unsigned short* h16b = (unsigned short*)(ws + 145227776);    //    524288 B
    unsigned*       slots= (unsigned*)(ws + 145752064);          //      1024 B
    unsigned*       rel  = (unsigned*)(ws + 145753088);          //      1024 B

    auto cast = [&](const float* s, unsigned short* d, int n) {
        int n4 = n >> 2;
        int blocks = (n4 + 255) / 256;
        if (blocks > 4096) blocks = 4096;
        k_cast_bf16<<<blocks, 256, 0, stream>>>(s, d, n4);
    };
    cast(x,   x16, 67108864);
    cast(Whr, wh,            1048576);
    cast(Whc, wh + 1048576,  1048576);
    cast(Whz, wh + 2097152,  1048576);
    cast(Wxr, wx,            524288);
    cast(Wxc, wx + 524288,   524288);
    cast(Wxz, wx + 1048576,  524288);
    cast(Wo,  wo16,          524288);

    hipMemsetAsync(h16a, 0, 524288, stream);
    hipMemsetAsync(slots, 0, 2048, stream);   // slots + rel

    hipFuncSetAttribute(reinterpret_cast<const void*>(k_gru),
                        hipFuncAttributeMaxDynamicSharedMemorySize, 147456);
    k_gru<<<dim3(256), dim3(256), 147456, stream>>>(
        x16, wh, wx, wo16, bxr, bhr, bxc, bhc, bxz, bhz, bo,
        h16a, h16b, slots, rel, (float*)d_out);
}

// Round 4
// 5030.581 us; speedup vs baseline: 5.0520x; 1.1806x over previous
//
#include <hip/hip_runtime.h>

typedef __attribute__((ext_vector_type(8))) short s16x8;
typedef __attribute__((ext_vector_type(4))) float f32x4;

#define SCOPE_AGENT __HIP_MEMORY_SCOPE_AGENT

static __device__ __forceinline__ unsigned short f2bf(float f) {
    unsigned u = __float_as_uint(f);
    u = (u + 0x7fffu + ((u >> 16) & 1u)) >> 16;
    return (unsigned short)u;
}

static __device__ __forceinline__ unsigned ld_sc1(const unsigned* p) {
    return __hip_atomic_load(p, __ATOMIC_RELAXED, SCOPE_AGENT);
}
static __device__ __forceinline__ void st_sc1(unsigned* p, unsigned v) {
    __hip_atomic_store(p, v, __ATOMIC_RELAXED, SCOPE_AGENT);
}

__global__ void k_cast_bf16(const float* __restrict__ src,
                            unsigned short* __restrict__ dst, int n4) {
    int i = blockIdx.x * blockDim.x + threadIdx.x;
    int stride = gridDim.x * blockDim.x;
    for (; i < n4; i += stride) {
        float4 v = reinterpret_cast<const float4*>(src)[i];
        ushort4 o;
        o.x = f2bf(v.x); o.y = f2bf(v.y); o.z = f2bf(v.z); o.w = f2bf(v.w);
        reinterpret_cast<ushort4*>(dst)[i] = o;
    }
}

// Persistent GRU: 256 blocks x 256 threads. Block (rb, jt): batch rows
// [rb*64,+64), hidden cols [jt*16,+16). Weights in LDS (147KB, swizzled).
// h stores: sc1 (MALL authoritative, L2 never dirty for h). h loads: NORMAL
// cached loads, made safe by an agent-scope ACQUIRE (buffer_inv) after the
// release word is seen -> 32 WGs/XCD share one L2 copy of the h slab.
__global__ __launch_bounds__(256, 1) void k_gru(
    const unsigned short* __restrict__ x16,    // [256][512][512] bf16
    const unsigned short* __restrict__ wh,     // [3][1024][1024]
    const unsigned short* __restrict__ wx,     // [3][1024][512]
    const unsigned short* __restrict__ wo,     // [512][1024]
    const float* __restrict__ bxr_, const float* __restrict__ bhr_,
    const float* __restrict__ bxc_, const float* __restrict__ bhc_,
    const float* __restrict__ bxz_, const float* __restrict__ bhz_,
    const float* __restrict__ bo_,
    unsigned short* __restrict__ h16a,         // [256][1024] bf16, zeroed
    unsigned short* __restrict__ h16b,
    unsigned* __restrict__ slots,              // [4][64] monotone flags, zeroed
    unsigned* __restrict__ rel,                // [4] release words (256B apart)
    float* __restrict__ out)                   // [256][512]
{
    extern __shared__ unsigned short lds[];

    const int tid = threadIdx.x;
    const int bid = blockIdx.x;
    const int xcd = bid & 7;
    const int rb  = xcd >> 1;
    const int jt  = ((bid >> 3) << 1) | (xcd & 1);
    const int b0  = rb * 64;
    const int j0  = jt * 16;

    // ---- stage weight tile into LDS once ----
    for (int i = 0; i < 36; ++i) {
        int gidx = i * 256 + tid;
        int rr = gidx / 192;
        int gc = gidx - rr * 192;
        int k  = gc << 3;
        int gate = rr >> 4;
        int j = j0 + (rr & 15);
        const unsigned short* src =
            (k < 1024) ? (wh + ((size_t)gate << 20) + ((size_t)j << 10) + k)
                       : (wx + (size_t)gate * 524288 + ((size_t)j << 9) + (k - 1024));
        s16x8 v = *reinterpret_cast<const s16x8*>(src);
        int boff = ((rr * 192 + gc) << 4) ^ ((rr & 7) << 4);
        *reinterpret_cast<s16x8*>(reinterpret_cast<char*>(lds) + boff) = v;
    }
    __syncthreads();

    const int lane = tid & 63;
    const int wv   = tid >> 6;
    const int l15  = lane & 15;
    const int lk   = lane >> 4;

    const int b   = b0 + wv * 16 + l15;
    const int jq  = j0 + lk * 4;
    const int swz = (l15 & 7) << 4;
    const int rbase0 = (l15)      * 192 + lk;
    const int rbase1 = (16 + l15) * 192 + lk;
    const int rbase2 = (32 + l15) * 192 + lk;

    float bR[4], bZ[4], bCh[4], bCx[4];
#pragma unroll
    for (int e = 0; e < 4; ++e) {
        int j = jq + e;
        bR[e]  = bxr_[j] + bhr_[j];
        bZ[e]  = bxz_[j] + bhz_[j];
        bCh[e] = bhc_[j];
        bCx[e] = bxc_[j];
    }

    float hreg[4] = {0.f, 0.f, 0.f, 0.f};
    char* lb = reinterpret_cast<char*>(lds);
    const unsigned short* xrowbase = x16 + (size_t)b * 262144 + lk * 8;
    unsigned* myflag  = &slots[(rb << 6) + jt];
    unsigned* grel    = &rel[rb << 6];

    // ---- prologue: x-part accumulators for t=0 ----
    f32x4 xR = {0.f,0.f,0.f,0.f}, xZ = {0.f,0.f,0.f,0.f}, xC = {0.f,0.f,0.f,0.f};
    {
        s16x8 xf[16];
#pragma unroll
        for (int kk = 0; kk < 16; ++kk)
            xf[kk] = *reinterpret_cast<const s16x8*>(xrowbase + kk * 32);
#pragma unroll
        for (int kk = 0; kk < 16; ++kk) {
            s16x8 w0 = *reinterpret_cast<s16x8*>(lb + (((rbase0 + (kk + 32) * 4) << 4) ^ swz));
            s16x8 w1 = *reinterpret_cast<s16x8*>(lb + (((rbase1 + (kk + 32) * 4) << 4) ^ swz));
            s16x8 w2 = *reinterpret_cast<s16x8*>(lb + (((rbase2 + (kk + 32) * 4) << 4) ^ swz));
            xR = __builtin_amdgcn_mfma_f32_16x16x32_bf16(w0, xf[kk], xR, 0, 0, 0);
            xC = __builtin_amdgcn_mfma_f32_16x16x32_bf16(w1, xf[kk], xC, 0, 0, 0);
            xZ = __builtin_amdgcn_mfma_f32_16x16x32_bf16(w2, xf[kk], xZ, 0, 0, 0);
        }
    }

    unsigned short* hc = h16a;                 // holds h_t (h_0 zeroed)
    unsigned short* hn = h16b;

    for (int t = 0; t < 512; ++t) {
        // ---- wait for h_t; ACQUIRE (emits buffer_inv: L1+L2) makes cached
        //      h loads fresh. Any L2 h-line is a clean copy of MALL, so the
        //      invalidate is always safe regardless of other WGs' progress.
        if (wv == 0) {
            while (ld_sc1(grel) < (unsigned)t) __builtin_amdgcn_s_sleep(1);
            (void)__hip_atomic_load(grel, __ATOMIC_ACQUIRE, SCOPE_AGENT);
        }
        __syncthreads();
        asm volatile("" ::: "memory");

        // ---- load h_t fragments: NORMAL cached 16B loads (L2-shared) ----
        s16x8 hf[32];
        const unsigned short* hrow = hc + ((size_t)b << 10) + lk * 8;
#pragma unroll
        for (int kk = 0; kk < 32; ++kk)
            hf[kk] = *reinterpret_cast<const s16x8*>(hrow + kk * 32);

        // ---- prefetch x fragments for t+1 (consumed post-barrier) ----
        s16x8 xfn[16];
        if (t < 511) {
            const unsigned short* axn = xrowbase + (size_t)(t + 1) * 512;
#pragma unroll
            for (int kk = 0; kk < 16; ++kk)
                xfn[kk] = *reinterpret_cast<const s16x8*>(axn + kk * 32);
        }

        // ---- h-part MFMAs, accs seeded from x-part ----
        f32x4 aR = xR, aZ = xZ, aCx = xC;
        f32x4 aCh = {0.f,0.f,0.f,0.f};
#pragma unroll
        for (int kk = 0; kk < 32; ++kk) {
            s16x8 w0 = *reinterpret_cast<s16x8*>(lb + (((rbase0 + kk * 4) << 4) ^ swz));
            s16x8 w1 = *reinterpret_cast<s16x8*>(lb + (((rbase1 + kk * 4) << 4) ^ swz));
            s16x8 w2 = *reinterpret_cast<s16x8*>(lb + (((rbase2 + kk * 4) << 4) ^ swz));
            aR  = __builtin_amdgcn_mfma_f32_16x16x32_bf16(w0, hf[kk], aR, 0, 0, 0);
            aCh = __builtin_amdgcn_mfma_f32_16x16x32_bf16(w1, hf[kk], aCh, 0, 0, 0);
            aZ  = __builtin_amdgcn_mfma_f32_16x16x32_bf16(w2, hf[kk], aZ, 0, 0, 0);
        }

        // ---- gate math; store own h_{t+1} (sc1 -> MALL, bypasses L2) ----
        unsigned long long pack = 0ull;
#pragma unroll
        for (int e = 0; e < 4; ++e) {
            float r   = __builtin_amdgcn_rcpf(1.f + __expf(-(aR[e] + bR[e])));
            float zg  = __builtin_amdgcn_rcpf(1.f + __expf(-(aZ[e] + bZ[e])));
            float u2  = aCx[e] + bCx[e] + r * (aCh[e] + bCh[e]);
            float cg  = 1.f - 2.f * __builtin_amdgcn_rcpf(__expf(2.f * u2) + 1.f);
            float hnv = (1.f - zg) * hreg[e] + zg * cg;
            hreg[e] = hnv;
            pack |= (unsigned long long)f2bf(hnv) << (16 * e);
        }
        __hip_atomic_store(
            reinterpret_cast<unsigned long long*>(hn + ((size_t)b << 10) + jq),
            pack, __ATOMIC_RELAXED, SCOPE_AGENT);

        __syncthreads();   // drains vmcnt(0): h store + xfn loads complete
        if (tid == 0) st_sc1(myflag, (unsigned)(t + 1));

        // ---- master aggregates flags -> release ----
        if (jt == 0 && wv == 0) {
            const unsigned tgt = (unsigned)(t + 1);
            for (;;) {
                unsigned v = ld_sc1(&slots[(rb << 6) + lane]);
                if (__all((int)(v >= tgt))) break;
                __builtin_amdgcn_s_sleep(1);
            }
            if (tid == 0) st_sc1(grel, tgt);
        }

        // ---- x-part MFMAs for t+1 (overlaps barrier wait of others) ----
        if (t < 511) {
            xR = {0.f,0.f,0.f,0.f}; xZ = {0.f,0.f,0.f,0.f}; xC = {0.f,0.f,0.f,0.f};
#pragma unroll
            for (int kk = 0; kk < 16; ++kk) {
                s16x8 w0 = *reinterpret_cast<s16x8*>(lb + (((rbase0 + (kk + 32) * 4) << 4) ^ swz));
                s16x8 w1 = *reinterpret_cast<s16x8*>(lb + (((rbase1 + (kk + 32) * 4) << 4) ^ swz));
                s16x8 w2 = *reinterpret_cast<s16x8*>(lb + (((rbase2 + (kk + 32) * 4) << 4) ^ swz));
                xR = __builtin_amdgcn_mfma_f32_16x16x32_bf16(w0, xfn[kk], xR, 0, 0, 0);
                xC = __builtin_amdgcn_mfma_f32_16x16x32_bf16(w1, xfn[kk], xC, 0, 0, 0);
                xZ = __builtin_amdgcn_mfma_f32_16x16x32_bf16(w2, xfn[kk], xZ, 0, 0, 0);
            }
        }

        unsigned short* tmp = hc; hc = hn; hn = tmp;
    }

    // ---- wait for full h_512, then output projection ----
    if (wv == 0) {
        while (ld_sc1(grel) < 512u) __builtin_amdgcn_s_sleep(1);
        (void)__hip_atomic_load(grel, __ATOMIC_ACQUIRE, SCOPE_AGENT);
    }
    __syncthreads();
    asm volatile("" ::: "memory");

    const int ocol  = jt * 8 + l15;
    const int ocolc = (l15 < 8) ? ocol : (jt * 8 + 7);
    f32x4 aO = {0.f,0.f,0.f,0.f};
    const unsigned short* hrow = hc + ((size_t)b << 10) + lk * 8;
    const unsigned short* bw = wo + ((size_t)ocolc << 10) + lk * 8;
#pragma unroll
    for (int kk = 0; kk < 32; ++kk) {
        s16x8 hv = *reinterpret_cast<const s16x8*>(hrow + kk * 32);
        s16x8 wb = *reinterpret_cast<const s16x8*>(bw + kk * 32);
        aO = __builtin_amdgcn_mfma_f32_16x16x32_bf16(hv, wb, aO, 0, 0, 0);
    }
    if (l15 < 8) {
        const float bov = bo_[ocol];
#pragma unroll
        for (int e = 0; e < 4; ++e) {
            out[((size_t)(b0 + wv * 16 + lk * 4 + e) << 9) + ocol] = aO[e] + bov;
        }
    }
}

extern "C" void kernel_launch(void* const* d_in, const int* in_sizes, int n_in,
                              void* d_out, int out_size, void* d_ws, size_t ws_size,
                              hipStream_t stream) {
    const float* x   = (const float*)d_in[0];
    const float* Wxr = (const float*)d_in[1];
    const float* bxr = (const float*)d_in[2];
    const float* Whr = (const float*)d_in[3];
    const float* bhr = (const float*)d_in[4];
    const float* Wxc = (const float*)d_in[5];
    const float* bxc = (const float*)d_in[6];
    const float* Whc = (const float*)d_in[7];
    const float* bhc = (const float*)d_in[8];
    const float* Wxz = (const float*)d_in[9];
    const float* bxz = (const float*)d_in[10];
    const float* Whz = (const float*)d_in[11];
    const float* bhz = (const float*)d_in[12];
    const float* Wo  = (const float*)d_in[13];
    const float* bo  = (const float*)d_in[14];

    char* ws = (char*)d_ws;
    unsigned short* x16  = (unsigned short*)(ws);                // 134217728 B
    unsigned short* wh   = (unsigned short*)(ws + 134217728);    //   6291456 B
    unsigned short* wx   = (unsigned short*)(ws + 140509184);    //   3145728 B
    unsigned short* wo16 = (unsigned short*)(ws + 143654912);    //   1048576 B
    unsigned short* h16a = (unsigned short*)(ws + 144703488);    //    524288 B
    unsigned short* h16b = (unsigned short*)(ws + 145227776);    //    524288 B
    unsigned*       slots= (unsigned*)(ws + 145752064);          //      1024 B
    unsigned*       rel  = (unsigned*)(ws + 145753088);          //      1024 B

    auto cast = [&](const float* s, unsigned short* d, int n) {
        int n4 = n >> 2;
        int blocks = (n4 + 255) / 256;
        if (blocks > 4096) blocks = 4096;
        k_cast_bf16<<<blocks, 256, 0, stream>>>(s, d, n4);
    };
    cast(x,   x16, 67108864);
    cast(Whr, wh,            1048576);
    cast(Whc, wh + 1048576,  1048576);
    cast(Whz, wh + 2097152,  1048576);
    cast(Wxr, wx,            524288);
    cast(Wxc, wx + 524288,   524288);
    cast(Wxz, wx + 1048576,  524288);
    cast(Wo,  wo16,          524288);

    hipMemsetAsync(h16a, 0, 524288, stream);
    hipMemsetAsync(slots, 0, 2048, stream);   // slots + rel

    hipFuncSetAttribute(reinterpret_cast<const void*>(k_gru),
                        hipFuncAttributeMaxDynamicSharedMemorySize, 147456);
    k_gru<<<dim3(256), dim3(256), 147456, stream>>>(
        x16, wh, wx, wo16, bxr, bhr, bxc, bhc, bxz, bhz, bo,
        h16a, h16b, slots, rel, (float*)d_out);
}